// Round 8
// baseline (208.574 us; speedup 1.0000x reference)
//
#include <hip/hip_runtime.h>

// ArtNetwork: y = sigmoid(Wout @ tanh(W8 @ ... tanh(W1 @ tanh(Win@x+b)) ...))
// R9: ILP discriminator. R8 showed removing VALU-issue work (VALUBusy 95->89)
// does NOT reduce time -> not issue-bound. Candidates: trans-exec occupancy
// (then we're at the floor) vs dependency-latency (2 chains/wave too few).
//  - 4 tiles (64 points) per wave-iter: 4 independent MFMA->v4s chains.
//  - Output trick: awos[s] places Wout rows at C/D rows 4s..4s+2; the 4
//    output MFMAs CHAIN through one accumulator (C-in = prev acc, A=0 rows
//    contribute nothing). Lane (quad q, col p) then holds point (tile q, p)'s
//    3 channels in regs 0..2 -> epilogue on all 64 lanes, no shuffles/branch.
//  - Stores: 3 wave-wide dword stores (768 B contiguous) — reverts R8's
//    float3 store (WRITE_SIZE 49152->63962 KB amplification).
//  - crs[8] in LDS (R7-proven neutral) to keep VGPR ~80, no spill.
//  - Kept: x prefetched one grid-stride iteration ahead.
//  - 4096 blocks x 256 thr; 4 tiles (64 pts)/wave-iter; 4 iters/wave.

typedef float  f32x4 __attribute__((ext_vector_type(4)));
typedef __fp16 f16x4 __attribute__((ext_vector_type(4)));
typedef __fp16 f16x2 __attribute__((ext_vector_type(2)));

#define K2   2.8853900817779268f    // 2*log2(e): exp2(K2*z) = e^{2z}
#define KOUT (-1.4426950408889634f) // -log2(e):  exp2(KOUT*z) = e^{-z}

// v for 4 values: v_i = 1/(1+exp2(y_i)). One rcp via product tree.
// (tanh(z_i) = 1 - 2 v_i; the affine part is folded into the next layer.)
__device__ __forceinline__ f16x4 v4s(f32x4 y) {
    float e0 = __builtin_amdgcn_exp2f(y[0]);
    float e1 = __builtin_amdgcn_exp2f(y[1]);
    float e2 = __builtin_amdgcn_exp2f(y[2]);
    float e3 = __builtin_amdgcn_exp2f(y[3]);
    float d0 = e0 + 1.0f, d1 = e1 + 1.0f, d2 = e2 + 1.0f, d3 = e3 + 1.0f;
    float p01 = d0 * d1, p23 = d2 * d3;           // d in [1,2981]: prod <= 7.9e13
    float r   = __builtin_amdgcn_rcpf(p01 * p23);
    float i01 = r * p23, i23 = r * p01;           // 1/(d0*d1), 1/(d2*d3)
    float v0 = i01 * d1, v1 = i01 * d0;
    float v2 = i23 * d3, v3 = i23 * d2;           // 1/d_i
    f16x2 lo = __builtin_amdgcn_cvt_pkrtz(v0, v1);
    f16x2 hi = __builtin_amdgcn_cvt_pkrtz(v2, v3);
    return __builtin_shufflevector(lo, hi, 0, 1, 2, 3);
}

__global__ __launch_bounds__(256, 6)
void artnet_kernel(const float2* __restrict__ x,     // [N][2]
                   const float2* __restrict__ Win,   // [16][2]
                   const float*  __restrict__ bin,   // [16]
                   const float4* __restrict__ Wh,    // [8][16][16]
                   const float4* __restrict__ Wout,  // [3][16]
                   float* __restrict__ out,          // [N][3]
                   int nQuads, int nWaves)
{
    const int tid  = blockIdx.x * 256 + threadIdx.x;
    const int gw   = tid >> 6;            // global wave id
    const int lane = threadIdx.x & 63;
    const int row  = lane & 15;           // A-row m / point-col index
    const int quad = lane >> 4;           // 0..3

    // C-operands for the 8 hidden layers in LDS (broadcast reads):
    // crs_lds[l][r] = K2 * rowsum(W_l row r).
    __shared__ __align__(16) float crs_lds[8][16];

    // ---- Hidden layers: A = -2*K2*W (f16) in registers
    f16x4 aw[8];
#pragma unroll
    for (int l = 0; l < 8; ++l) {
        float4 w = Wh[l * 64 + row * 4 + quad];
        const float s = -2.0f * K2;
        f16x2 lo = __builtin_amdgcn_cvt_pkrtz(w.x * s, w.y * s);
        f16x2 hi = __builtin_amdgcn_cvt_pkrtz(w.z * s, w.w * s);
        aw[l] = __builtin_shufflevector(lo, hi, 0, 1, 2, 3);
        float partial = w.x + w.y + w.z + w.w;
        partial += __shfl_xor(partial, 16, 64);
        partial += __shfl_xor(partial, 32, 64);   // all quads of this row agree
        if (threadIdx.x < 16)                     // wave 0, quad 0: row == lane
            crs_lds[l][row] = K2 * partial;
    }

    // ---- Input layer: A[m=row][k] = {K2*Win.x, K2*Win.y, K2*b, 0} on quad 0
    f16x4 awin = {(__fp16)0.0f, (__fp16)0.0f, (__fp16)0.0f, (__fp16)0.0f};
    if (quad == 0) {
        float2 wr = Win[row];
        f16x2 lo = __builtin_amdgcn_cvt_pkrtz(wr.x * K2, wr.y * K2);
        f16x2 hi = __builtin_amdgcn_cvt_pkrtz(bin[row] * K2, 0.0f);
        awin = __builtin_shufflevector(lo, hi, 0, 1, 2, 3);
    }

    // ---- Output layer, tile-shifted A frags:
    //  awos[s] has A[m][k] = -2*KOUT*Wout[m-4s][k] for m in [4s,4s+3), else 0.
    //  With C/D row = quad*4+i, tile s's channel c lands on quad-s lanes reg c.
    const f16x4 zf16 = {(__fp16)0.0f, (__fp16)0.0f, (__fp16)0.0f, (__fp16)0.0f};
    f16x4 wobase = zf16;
    const int r3 = row & 3;
    if (r3 < 3) {
        float4 w = Wout[r3 * 4 + quad];
        const float s = -2.0f * KOUT;
        f16x2 lo = __builtin_amdgcn_cvt_pkrtz(w.x * s, w.y * s);
        f16x2 hi = __builtin_amdgcn_cvt_pkrtz(w.z * s, w.w * s);
        wobase = __builtin_shufflevector(lo, hi, 0, 1, 2, 3);
    }
    f16x4 awos[4];
#pragma unroll
    for (int s = 0; s < 4; ++s)
        awos[s] = ((row >> 2) == s) ? wobase : zf16;

    // crso[i] = KOUT*rowsum(Wout row i) for i<3, else 0 — same on ALL lanes.
    float prt = 0.0f;
    if (row < 3) {
        float4 w = Wout[row * 4 + quad];
        prt = w.x + w.y + w.z + w.w;
    }
    prt += __shfl_xor(prt, 16, 64);
    prt += __shfl_xor(prt, 32, 64);
    f32x4 crso;
#pragma unroll
    for (int i = 0; i < 4; ++i)
        crso[i] = (i < 3) ? KOUT * __shfl(prt, i, 64) : 0.0f;

    __syncthreads();   // crs_lds ready

    const f32x4 zero4 = {0.0f, 0.0f, 0.0f, 0.0f};
    const f16x2 one0  = {(__fp16)1.0f, (__fp16)0.0f};

    // ---- Main loop: 4 tiles (64 pts) per iter, x prefetched one iter ahead
    int qi = gw;
    float2 xp[4];
    if (qi < nQuads) {
#pragma unroll
        for (int s = 0; s < 4; ++s)
            xp[s] = x[(qi * 4 + s) * 16 + row];
    }

    while (qi < nQuads) {
        const int qn = qi + nWaves;

        // ---- Input B frags: B = {x, y, 1, *}; quad>0 is don't-care (A=0)
        f16x4 bf[4];
#pragma unroll
        for (int s = 0; s < 4; ++s) {
            f16x2 lo = __builtin_amdgcn_cvt_pkrtz(xp[s].x, xp[s].y);
            bf[s] = __builtin_shufflevector(lo, one0, 0, 1, 2, 3);
        }

        // ---- Prefetch next iteration's x
        if (qn < nQuads) {
#pragma unroll
            for (int s = 0; s < 4; ++s)
                xp[s] = x[(qn * 4 + s) * 16 + row];
        }

        // ---- Input layer: 4 independent chains
        f32x4 y0 = __builtin_amdgcn_mfma_f32_16x16x16f16(awin, bf[0], zero4, 0, 0, 0);
        f32x4 y1 = __builtin_amdgcn_mfma_f32_16x16x16f16(awin, bf[1], zero4, 0, 0, 0);
        f32x4 y2 = __builtin_amdgcn_mfma_f32_16x16x16f16(awin, bf[2], zero4, 0, 0, 0);
        f32x4 y3 = __builtin_amdgcn_mfma_f32_16x16x16f16(awin, bf[3], zero4, 0, 0, 0);
        bf[0] = v4s(y0); bf[1] = v4s(y1); bf[2] = v4s(y2); bf[3] = v4s(y3);

        // ---- 8 hidden layers: MFMA emits y' = K2*(W·1 - 2W@v) directly
#pragma unroll
        for (int l = 0; l < 8; ++l) {
            f32x4 c = *(const f32x4*)&crs_lds[l][quad * 4];
            f32x4 t0 = __builtin_amdgcn_mfma_f32_16x16x16f16(aw[l], bf[0], c, 0, 0, 0);
            f32x4 t1 = __builtin_amdgcn_mfma_f32_16x16x16f16(aw[l], bf[1], c, 0, 0, 0);
            f32x4 t2 = __builtin_amdgcn_mfma_f32_16x16x16f16(aw[l], bf[2], c, 0, 0, 0);
            f32x4 t3 = __builtin_amdgcn_mfma_f32_16x16x16f16(aw[l], bf[3], c, 0, 0, 0);
            bf[0] = v4s(t0); bf[1] = v4s(t1); bf[2] = v4s(t2); bf[3] = v4s(t3);
        }

        // ---- Output: chained MFMAs. Rows != 4s have A=0, so each tile adds
        //  only its own rows; final acc on lane (quad q, col p) = crso +
        //  tile-q contribution = KOUT*zout channels of point (tile q, p).
        f32x4 acc;
        acc = __builtin_amdgcn_mfma_f32_16x16x16f16(awos[0], bf[0], crso, 0, 0, 0);
        acc = __builtin_amdgcn_mfma_f32_16x16x16f16(awos[1], bf[1], acc,  0, 0, 0);
        acc = __builtin_amdgcn_mfma_f32_16x16x16f16(awos[2], bf[2], acc,  0, 0, 0);
        acc = __builtin_amdgcn_mfma_f32_16x16x16f16(awos[3], bf[3], acc,  0, 0, 0);

        // ---- Sigmoid epilogue on ALL 64 lanes: 3 exp2 + 1 rcp per point
        {
            float d0 = __builtin_amdgcn_exp2f(acc[0]) + 1.0f;
            float d1 = __builtin_amdgcn_exp2f(acc[1]) + 1.0f;
            float d2 = __builtin_amdgcn_exp2f(acc[2]) + 1.0f;
            float p01 = d0 * d1;                        // d <= ~331: P3 <= 3.6e7
            float r   = __builtin_amdgcn_rcpf(p01 * d2);
            float s2  = r * p01;                        // 1/d2
            float t   = r * d2;                         // 1/(d0*d1)
            float s0  = t * d1, s1 = t * d0;            // 1/d0, 1/d1
            const int p = (qi * 4 + quad) * 16 + row;   // quad == tile index
            out[p * 3 + 0] = s0;
            out[p * 3 + 1] = s1;
            out[p * 3 + 2] = s2;
        }

        qi = qn;
    }
}

extern "C" void kernel_launch(void* const* d_in, const int* in_sizes, int n_in,
                              void* d_out, int out_size, void* d_ws, size_t ws_size,
                              hipStream_t stream) {
    const float2* x    = (const float2*)d_in[0];
    const float2* Win  = (const float2*)d_in[1];
    const float*  bin  = (const float*) d_in[2];
    const float4* Wh   = (const float4*)d_in[3];
    const float4* Wout = (const float4*)d_in[4];
    float* out = (float*)d_out;

    const int n      = in_sizes[0] / 2;   // 4,194,304 points
    const int nQuads = n / 64;            // 4 tiles of 16 points per wave-iter
    const int blocks = 4096;              // 16384 waves, 4 iters/wave, no tail
    const int nWaves = blocks * 4;

    artnet_kernel<<<blocks, 256, 0, stream>>>(x, Win, bin, Wh, Wout, out, nQuads, nWaves);
}

// Round 10
// 192.553 us; speedup vs baseline: 1.0832x; 1.0832x over previous
//
#include <hip/hip_runtime.h>

// ArtNetwork: y = sigmoid(Wout @ tanh(W8 @ ... tanh(W1 @ tanh(Win@x+b)) ...))
// R10: R9's 4-chain ILP test, DE-SPILLED. R9 regressed (143us) because
// __launch_bounds__(256,6) caps VGPRs at ~84; 4 interleaved chains need
// ~110+ -> scratch spills (WRITE_SIZE 49->196 MB, FETCH 20->70 MB = spill
// stores + reloads, ~1.9 TB/s of pure waste). R9 WAS numerically exact
// (absmax 0.0), so the structure stands; only the register cap changes:
//  - __launch_bounds__(256, 4): VGPR cap 128, min 4 waves/SIMD (measured
//    residency was ~4.4 anyway -> occupancy cost ~0, spills gone).
//  - 4 tiles (64 points) per wave-iter: 4 independent MFMA->v4s chains.
//  - Output trick: awos[s] places Wout rows at C/D rows 4s..4s+2; the 4
//    output MFMAs CHAIN through one accumulator. Lane (quad q, col p) holds
//    point (tile q, p)'s 3 channels -> epilogue on all 64 lanes, no shuffles.
//  - crs[8] in LDS (broadcast reads); aw[8] stays in regs.
//  - x prefetched one grid-stride iteration ahead.
//  - 4096 blocks x 256 thr; 4 tiles (64 pts)/wave-iter; 4 iters/wave.
// Spill detector for the post-mortem: WRITE_SIZE ~49MB & FETCH ~20MB = clean;
// anything above = still spilling (or the stride-12 store pattern is at fault).

typedef float  f32x4 __attribute__((ext_vector_type(4)));
typedef __fp16 f16x4 __attribute__((ext_vector_type(4)));
typedef __fp16 f16x2 __attribute__((ext_vector_type(2)));

#define K2   2.8853900817779268f    // 2*log2(e): exp2(K2*z) = e^{2z}
#define KOUT (-1.4426950408889634f) // -log2(e):  exp2(KOUT*z) = e^{-z}

// v for 4 values: v_i = 1/(1+exp2(y_i)). One rcp via product tree.
// (tanh(z_i) = 1 - 2 v_i; the affine part is folded into the next layer.)
__device__ __forceinline__ f16x4 v4s(f32x4 y) {
    float e0 = __builtin_amdgcn_exp2f(y[0]);
    float e1 = __builtin_amdgcn_exp2f(y[1]);
    float e2 = __builtin_amdgcn_exp2f(y[2]);
    float e3 = __builtin_amdgcn_exp2f(y[3]);
    float d0 = e0 + 1.0f, d1 = e1 + 1.0f, d2 = e2 + 1.0f, d3 = e3 + 1.0f;
    float p01 = d0 * d1, p23 = d2 * d3;           // d in [1,2981]: prod <= 7.9e13
    float r   = __builtin_amdgcn_rcpf(p01 * p23);
    float i01 = r * p23, i23 = r * p01;           // 1/(d0*d1), 1/(d2*d3)
    float v0 = i01 * d1, v1 = i01 * d0;
    float v2 = i23 * d3, v3 = i23 * d2;           // 1/d_i
    f16x2 lo = __builtin_amdgcn_cvt_pkrtz(v0, v1);
    f16x2 hi = __builtin_amdgcn_cvt_pkrtz(v2, v3);
    return __builtin_shufflevector(lo, hi, 0, 1, 2, 3);
}

__global__ __launch_bounds__(256, 4)
void artnet_kernel(const float2* __restrict__ x,     // [N][2]
                   const float2* __restrict__ Win,   // [16][2]
                   const float*  __restrict__ bin,   // [16]
                   const float4* __restrict__ Wh,    // [8][16][16]
                   const float4* __restrict__ Wout,  // [3][16]
                   float* __restrict__ out,          // [N][3]
                   int nQuads, int nWaves)
{
    const int tid  = blockIdx.x * 256 + threadIdx.x;
    const int gw   = tid >> 6;            // global wave id
    const int lane = threadIdx.x & 63;
    const int row  = lane & 15;           // A-row m / point-col index
    const int quad = lane >> 4;           // 0..3

    // C-operands for the 8 hidden layers in LDS (broadcast reads):
    // crs_lds[l][r] = K2 * rowsum(W_l row r).
    __shared__ __align__(16) float crs_lds[8][16];

    // ---- Hidden layers: A = -2*K2*W (f16) in registers
    f16x4 aw[8];
#pragma unroll
    for (int l = 0; l < 8; ++l) {
        float4 w = Wh[l * 64 + row * 4 + quad];
        const float s = -2.0f * K2;
        f16x2 lo = __builtin_amdgcn_cvt_pkrtz(w.x * s, w.y * s);
        f16x2 hi = __builtin_amdgcn_cvt_pkrtz(w.z * s, w.w * s);
        aw[l] = __builtin_shufflevector(lo, hi, 0, 1, 2, 3);
        float partial = w.x + w.y + w.z + w.w;
        partial += __shfl_xor(partial, 16, 64);
        partial += __shfl_xor(partial, 32, 64);   // all quads of this row agree
        if (threadIdx.x < 16)                     // wave 0, quad 0: row == lane
            crs_lds[l][row] = K2 * partial;
    }

    // ---- Input layer: A[m=row][k] = {K2*Win.x, K2*Win.y, K2*b, 0} on quad 0
    f16x4 awin = {(__fp16)0.0f, (__fp16)0.0f, (__fp16)0.0f, (__fp16)0.0f};
    if (quad == 0) {
        float2 wr = Win[row];
        f16x2 lo = __builtin_amdgcn_cvt_pkrtz(wr.x * K2, wr.y * K2);
        f16x2 hi = __builtin_amdgcn_cvt_pkrtz(bin[row] * K2, 0.0f);
        awin = __builtin_shufflevector(lo, hi, 0, 1, 2, 3);
    }

    // ---- Output layer, tile-shifted A frags:
    //  awos[s] has A[m][k] = -2*KOUT*Wout[m-4s][k] for m in [4s,4s+3), else 0.
    //  With C/D row = quad*4+i, tile s's channel c lands on quad-s lanes reg c.
    const f16x4 zf16 = {(__fp16)0.0f, (__fp16)0.0f, (__fp16)0.0f, (__fp16)0.0f};
    f16x4 wobase = zf16;
    const int r3 = row & 3;
    if (r3 < 3) {
        float4 w = Wout[r3 * 4 + quad];
        const float s = -2.0f * KOUT;
        f16x2 lo = __builtin_amdgcn_cvt_pkrtz(w.x * s, w.y * s);
        f16x2 hi = __builtin_amdgcn_cvt_pkrtz(w.z * s, w.w * s);
        wobase = __builtin_shufflevector(lo, hi, 0, 1, 2, 3);
    }
    f16x4 awos[4];
#pragma unroll
    for (int s = 0; s < 4; ++s)
        awos[s] = ((row >> 2) == s) ? wobase : zf16;

    // crso[i] = KOUT*rowsum(Wout row i) for i<3, else 0 — same on ALL lanes.
    float prt = 0.0f;
    if (row < 3) {
        float4 w = Wout[row * 4 + quad];
        prt = w.x + w.y + w.z + w.w;
    }
    prt += __shfl_xor(prt, 16, 64);
    prt += __shfl_xor(prt, 32, 64);
    f32x4 crso;
#pragma unroll
    for (int i = 0; i < 4; ++i)
        crso[i] = (i < 3) ? KOUT * __shfl(prt, i, 64) : 0.0f;

    __syncthreads();   // crs_lds ready

    const f32x4 zero4 = {0.0f, 0.0f, 0.0f, 0.0f};
    const f16x2 one0  = {(__fp16)1.0f, (__fp16)0.0f};

    // ---- Main loop: 4 tiles (64 pts) per iter, x prefetched one iter ahead
    int qi = gw;
    float2 xp[4];
    if (qi < nQuads) {
#pragma unroll
        for (int s = 0; s < 4; ++s)
            xp[s] = x[(qi * 4 + s) * 16 + row];
    }

    while (qi < nQuads) {
        const int qn = qi + nWaves;

        // ---- Input B frags: B = {x, y, 1, *}; quad>0 is don't-care (A=0)
        f16x4 bf[4];
#pragma unroll
        for (int s = 0; s < 4; ++s) {
            f16x2 lo = __builtin_amdgcn_cvt_pkrtz(xp[s].x, xp[s].y);
            bf[s] = __builtin_shufflevector(lo, one0, 0, 1, 2, 3);
        }

        // ---- Prefetch next iteration's x
        if (qn < nQuads) {
#pragma unroll
            for (int s = 0; s < 4; ++s)
                xp[s] = x[(qn * 4 + s) * 16 + row];
        }

        // ---- Input layer: 4 independent chains
        f32x4 y0 = __builtin_amdgcn_mfma_f32_16x16x16f16(awin, bf[0], zero4, 0, 0, 0);
        f32x4 y1 = __builtin_amdgcn_mfma_f32_16x16x16f16(awin, bf[1], zero4, 0, 0, 0);
        f32x4 y2 = __builtin_amdgcn_mfma_f32_16x16x16f16(awin, bf[2], zero4, 0, 0, 0);
        f32x4 y3 = __builtin_amdgcn_mfma_f32_16x16x16f16(awin, bf[3], zero4, 0, 0, 0);
        bf[0] = v4s(y0); bf[1] = v4s(y1); bf[2] = v4s(y2); bf[3] = v4s(y3);

        // ---- 8 hidden layers: MFMA emits y' = K2*(W·1 - 2W@v) directly
#pragma unroll
        for (int l = 0; l < 8; ++l) {
            f32x4 c = *(const f32x4*)&crs_lds[l][quad * 4];
            f32x4 t0 = __builtin_amdgcn_mfma_f32_16x16x16f16(aw[l], bf[0], c, 0, 0, 0);
            f32x4 t1 = __builtin_amdgcn_mfma_f32_16x16x16f16(aw[l], bf[1], c, 0, 0, 0);
            f32x4 t2 = __builtin_amdgcn_mfma_f32_16x16x16f16(aw[l], bf[2], c, 0, 0, 0);
            f32x4 t3 = __builtin_amdgcn_mfma_f32_16x16x16f16(aw[l], bf[3], c, 0, 0, 0);
            bf[0] = v4s(t0); bf[1] = v4s(t1); bf[2] = v4s(t2); bf[3] = v4s(t3);
        }

        // ---- Output: chained MFMAs. Rows != 4s have A=0, so each tile adds
        //  only its own rows; final acc on lane (quad q, col p) = crso +
        //  tile-q contribution = KOUT*zout channels of point (tile q, p).
        f32x4 acc;
        acc = __builtin_amdgcn_mfma_f32_16x16x16f16(awos[0], bf[0], crso, 0, 0, 0);
        acc = __builtin_amdgcn_mfma_f32_16x16x16f16(awos[1], bf[1], acc,  0, 0, 0);
        acc = __builtin_amdgcn_mfma_f32_16x16x16f16(awos[2], bf[2], acc,  0, 0, 0);
        acc = __builtin_amdgcn_mfma_f32_16x16x16f16(awos[3], bf[3], acc,  0, 0, 0);

        // ---- Sigmoid epilogue on ALL 64 lanes: 3 exp2 + 1 rcp per point
        {
            float d0 = __builtin_amdgcn_exp2f(acc[0]) + 1.0f;
            float d1 = __builtin_amdgcn_exp2f(acc[1]) + 1.0f;
            float d2 = __builtin_amdgcn_exp2f(acc[2]) + 1.0f;
            float p01 = d0 * d1;                        // d <= ~331: P3 <= 3.6e7
            float r   = __builtin_amdgcn_rcpf(p01 * d2);
            float s2  = r * p01;                        // 1/d2
            float t   = r * d2;                         // 1/(d0*d1)
            float s0  = t * d1, s1 = t * d0;            // 1/d0, 1/d1
            const int p = (qi * 4 + quad) * 16 + row;   // quad == tile index
            out[p * 3 + 0] = s0;
            out[p * 3 + 1] = s1;
            out[p * 3 + 2] = s2;
        }

        qi = qn;
    }
}

extern "C" void kernel_launch(void* const* d_in, const int* in_sizes, int n_in,
                              void* d_out, int out_size, void* d_ws, size_t ws_size,
                              hipStream_t stream) {
    const float2* x    = (const float2*)d_in[0];
    const float2* Win  = (const float2*)d_in[1];
    const float*  bin  = (const float*) d_in[2];
    const float4* Wh   = (const float4*)d_in[3];
    const float4* Wout = (const float4*)d_in[4];
    float* out = (float*)d_out;

    const int n      = in_sizes[0] / 2;   // 4,194,304 points
    const int nQuads = n / 64;            // 4 tiles of 16 points per wave-iter
    const int blocks = 4096;              // 16384 waves, 4 iters/wave, no tail
    const int nWaves = blocks * 4;

    artnet_kernel<<<blocks, 256, 0, stream>>>(x, Win, bin, Wh, Wout, out, nQuads, nWaves);
}

// Round 15
// 188.050 us; speedup vs baseline: 1.1091x; 1.0239x over previous
//
#include <hip/hip_runtime.h>

// ArtNetwork: y = sigmoid(Wout @ tanh(W8 @ ... tanh(W1 @ tanh(Win@x+b)) ...))
// R11: consolidation under the exec-throughput model. Evidence: busy-time
// (dur x VALUBusy) ~115-120us across R7/R8/R10 regardless of ILP (R10),
// issue shaving (R8), occupancy -> VALU EXECUTION bound, trans-dominated
// (~16 cyc/wave64 inferred; 184 trans wave-ops per 64 pts = ~68% of work).
//  - v8s: ONE rcp per 8 activations (8-wide product tree, both tiles).
//    18 -> 9 rcp/pair-iter. P8 <= 3101^8 = 8.5e27 < f32 max. Discriminator:
//    -144 cyc/pair-iter if trans=16cyc, -72 if trans=8.
//  - Epilogue via chained tile-shifted output MFMAs (R9/R10-proven exact):
//    awos2[s] puts Wout rows at C/D rows 4s..4s+2 -> tile s lands on quad s;
//    no shuffles, no selects (R8 epilogue had 3 shfl + cndmasks).
//  - 2-tile loop + __launch_bounds__(256,6) (best measured busy%: R7 95%),
//    crs[8] in LDS (R7-proven), dword stores (proven WRITE=49152KB clean),
//    x prefetched one grid-stride iteration ahead.
//  - 4096 blocks x 256 thr; 2 tiles (32 pts)/wave-iter; 8 iters/wave.
// Post-mortem keys: WRITE_SIZE must stay 49152KB (spill detector).
// dur>=122us & busy>=94% -> exec floor reached, roofline next round.

typedef float  f32x4 __attribute__((ext_vector_type(4)));
typedef __fp16 f16x4 __attribute__((ext_vector_type(4)));
typedef __fp16 f16x2 __attribute__((ext_vector_type(2)));

#define K2   2.8853900817779268f    // 2*log2(e): exp2(K2*z) = e^{2z}
#define KOUT (-1.4426950408889634f) // -log2(e):  exp2(KOUT*z) = e^{-z}

// v for 8 values (two f32x4 accs), ONE rcp via 8-wide product tree.
// v_i = 1/(1+exp2(y_i)); tanh(z) = 1-2v folded into next layer's A and C.
__device__ __forceinline__ void v8s(f32x4 ya, f32x4 yb, f16x4& va, f16x4& vb) {
    float e0 = __builtin_amdgcn_exp2f(ya[0]);
    float e1 = __builtin_amdgcn_exp2f(ya[1]);
    float e2 = __builtin_amdgcn_exp2f(ya[2]);
    float e3 = __builtin_amdgcn_exp2f(ya[3]);
    float e4 = __builtin_amdgcn_exp2f(yb[0]);
    float e5 = __builtin_amdgcn_exp2f(yb[1]);
    float e6 = __builtin_amdgcn_exp2f(yb[2]);
    float e7 = __builtin_amdgcn_exp2f(yb[3]);
    float d0 = e0 + 1.0f, d1 = e1 + 1.0f, d2 = e2 + 1.0f, d3 = e3 + 1.0f;
    float d4 = e4 + 1.0f, d5 = e5 + 1.0f, d6 = e6 + 1.0f, d7 = e7 + 1.0f;
    float p01 = d0 * d1, p23 = d2 * d3;     // d in [1,3101]: p <= 9.7e6
    float p45 = d4 * d5, p67 = d6 * d7;
    float q03 = p01 * p23, q47 = p45 * p67; // q <= 9.3e13
    float r   = __builtin_amdgcn_rcpf(q03 * q47);  // P8 <= 8.7e27, rcp >= 1.1e-28
    float rA  = r * q47, rB = r * q03;      // 1/q03, 1/q47
    float i01 = rA * p23, i23 = rA * p01;   // 1/p01, 1/p23
    float i45 = rB * p67, i67 = rB * p45;
    float v0 = i01 * d1, v1 = i01 * d0;
    float v2 = i23 * d3, v3 = i23 * d2;
    float v4 = i45 * d5, v5 = i45 * d4;
    float v6 = i67 * d7, v7 = i67 * d6;     // 1/d_i
    f16x2 la = __builtin_amdgcn_cvt_pkrtz(v0, v1);
    f16x2 ha = __builtin_amdgcn_cvt_pkrtz(v2, v3);
    f16x2 lb = __builtin_amdgcn_cvt_pkrtz(v4, v5);
    f16x2 hb = __builtin_amdgcn_cvt_pkrtz(v6, v7);
    va = __builtin_shufflevector(la, ha, 0, 1, 2, 3);
    vb = __builtin_shufflevector(lb, hb, 0, 1, 2, 3);
}

__global__ __launch_bounds__(256, 6)
void artnet_kernel(const float2* __restrict__ x,     // [N][2]
                   const float2* __restrict__ Win,   // [16][2]
                   const float*  __restrict__ bin,   // [16]
                   const float4* __restrict__ Wh,    // [8][16][16]
                   const float4* __restrict__ Wout,  // [3][16]
                   float* __restrict__ out,          // [N][3]
                   int nPairs, int nWaves)
{
    const int tid  = blockIdx.x * 256 + threadIdx.x;
    const int gw   = tid >> 6;            // global wave id
    const int lane = threadIdx.x & 63;
    const int row  = lane & 15;           // A-row m / point-col index
    const int quad = lane >> 4;           // 0..3

    // C-operands for the 8 hidden layers in LDS (broadcast reads):
    // crs_lds[l][r] = K2 * rowsum(W_l row r).
    __shared__ __align__(16) float crs_lds[8][16];

    // ---- Hidden layers: A = -2*K2*W (f16) in registers
    f16x4 aw[8];
#pragma unroll
    for (int l = 0; l < 8; ++l) {
        float4 w = Wh[l * 64 + row * 4 + quad];
        const float s = -2.0f * K2;
        f16x2 lo = __builtin_amdgcn_cvt_pkrtz(w.x * s, w.y * s);
        f16x2 hi = __builtin_amdgcn_cvt_pkrtz(w.z * s, w.w * s);
        aw[l] = __builtin_shufflevector(lo, hi, 0, 1, 2, 3);
        float partial = w.x + w.y + w.z + w.w;
        partial += __shfl_xor(partial, 16, 64);
        partial += __shfl_xor(partial, 32, 64);   // all quads of this row agree
        if (threadIdx.x < 16)                     // wave 0, quad 0: row == lane
            crs_lds[l][row] = K2 * partial;
    }

    // ---- Input layer: A[m=row][k] = {K2*Win.x, K2*Win.y, K2*b, 0} on quad 0
    f16x4 awin = {(__fp16)0.0f, (__fp16)0.0f, (__fp16)0.0f, (__fp16)0.0f};
    if (quad == 0) {
        float2 wr = Win[row];
        f16x2 lo = __builtin_amdgcn_cvt_pkrtz(wr.x * K2, wr.y * K2);
        f16x2 hi = __builtin_amdgcn_cvt_pkrtz(bin[row] * K2, 0.0f);
        awin = __builtin_shufflevector(lo, hi, 0, 1, 2, 3);
    }

    // ---- Output layer, tile-shifted A frags (R9/R10-proven):
    //  awos2[s]: A rows 4s..4s+2 = -2*KOUT*Wout rows 0..2, else 0.
    //  Tile s's channel c lands on quad-s lanes, C/D reg c.
    const f16x4 zf16 = {(__fp16)0.0f, (__fp16)0.0f, (__fp16)0.0f, (__fp16)0.0f};
    f16x4 wobase = zf16;
    const int r3 = row & 3;
    if (r3 < 3) {
        float4 w = Wout[r3 * 4 + quad];
        const float s = -2.0f * KOUT;
        f16x2 lo = __builtin_amdgcn_cvt_pkrtz(w.x * s, w.y * s);
        f16x2 hi = __builtin_amdgcn_cvt_pkrtz(w.z * s, w.w * s);
        wobase = __builtin_shufflevector(lo, hi, 0, 1, 2, 3);
    }
    f16x4 awos2[2];
    awos2[0] = ((row >> 2) == 0) ? wobase : zf16;   // rows 0..2 -> quad 0
    awos2[1] = ((row >> 2) == 1) ? wobase : zf16;   // rows 4..6 -> quad 1

    // crso[i] = KOUT*rowsum(Wout row i) for i<3, else 0 — same on ALL lanes.
    float prt = 0.0f;
    if (row < 3) {
        float4 w = Wout[row * 4 + quad];
        prt = w.x + w.y + w.z + w.w;
    }
    prt += __shfl_xor(prt, 16, 64);
    prt += __shfl_xor(prt, 32, 64);
    f32x4 crso;
#pragma unroll
    for (int i = 0; i < 4; ++i)
        crso[i] = (i < 3) ? KOUT * __shfl(prt, i, 64) : 0.0f;

    __syncthreads();   // crs_lds ready

    const f32x4 zero4 = {0.0f, 0.0f, 0.0f, 0.0f};
    const f16x2 one0  = {(__fp16)1.0f, (__fp16)0.0f};

    // ---- Main loop, x prefetched one grid-stride iteration ahead
    int pi = gw;
    float2 xa, xb;
    if (pi < nPairs) {
        xa = x[pi * 32 + row];
        xb = x[pi * 32 + 16 + row];
    }

    while (pi < nPairs) {
        const int pn = pi + nWaves;

        // ---- Input B frags: B = {x, y, 1, *}; quad>0 is don't-care (A=0)
        f16x2 la = __builtin_amdgcn_cvt_pkrtz(xa.x, xa.y);
        f16x2 lb = __builtin_amdgcn_cvt_pkrtz(xb.x, xb.y);
        f16x4 bf0 = __builtin_shufflevector(la, one0, 0, 1, 2, 3);
        f16x4 bf1 = __builtin_shufflevector(lb, one0, 0, 1, 2, 3);

        // ---- Prefetch next iteration's x
        if (pn < nPairs) {
            xa = x[pn * 32 + row];
            xb = x[pn * 32 + 16 + row];
        }

        // ---- Input layer
        f32x4 y0 = __builtin_amdgcn_mfma_f32_16x16x16f16(awin, bf0, zero4, 0, 0, 0);
        f32x4 y1 = __builtin_amdgcn_mfma_f32_16x16x16f16(awin, bf1, zero4, 0, 0, 0);
        v8s(y0, y1, bf0, bf1);

        // ---- 8 hidden layers: MFMA emits y' = K2*(W·1 - 2W@v) directly
#pragma unroll
        for (int l = 0; l < 8; ++l) {
            f32x4 c = *(const f32x4*)&crs_lds[l][quad * 4];
            f32x4 t0 = __builtin_amdgcn_mfma_f32_16x16x16f16(aw[l], bf0, c, 0, 0, 0);
            f32x4 t1 = __builtin_amdgcn_mfma_f32_16x16x16f16(aw[l], bf1, c, 0, 0, 0);
            v8s(t0, t1, bf0, bf1);
        }

        // ---- Output: chained tile-shifted MFMAs; quad q (q<2) ends with
        //  point (tile q, col row)'s 3 channels (KOUT*zout) in acc[0..2].
        f32x4 acc;
        acc = __builtin_amdgcn_mfma_f32_16x16x16f16(awos2[0], bf0, crso, 0, 0, 0);
        acc = __builtin_amdgcn_mfma_f32_16x16x16f16(awos2[1], bf1, acc,  0, 0, 0);

        // ---- Sigmoid epilogue on quads 0..1: 3 exp2 + 1 rcp per point
        if (quad < 2) {
            float d0 = __builtin_amdgcn_exp2f(acc[0]) + 1.0f;
            float d1 = __builtin_amdgcn_exp2f(acc[1]) + 1.0f;
            float d2 = __builtin_amdgcn_exp2f(acc[2]) + 1.0f;
            float p01 = d0 * d1;                        // d <= ~331: P3 <= 3.6e7
            float r   = __builtin_amdgcn_rcpf(p01 * d2);
            float s2  = r * p01;                        // 1/d2
            float t   = r * d2;                         // 1/(d0*d1)
            float s0  = t * d1, s1 = t * d0;            // 1/d0, 1/d1
            const int p = (pi * 2 + quad) * 16 + row;   // quad == tile index
            out[p * 3 + 0] = s0;
            out[p * 3 + 1] = s1;
            out[p * 3 + 2] = s2;
        }

        pi = pn;
    }
}

extern "C" void kernel_launch(void* const* d_in, const int* in_sizes, int n_in,
                              void* d_out, int out_size, void* d_ws, size_t ws_size,
                              hipStream_t stream) {
    const float2* x    = (const float2*)d_in[0];
    const float2* Win  = (const float2*)d_in[1];
    const float*  bin  = (const float*) d_in[2];
    const float4* Wh   = (const float4*)d_in[3];
    const float4* Wout = (const float4*)d_in[4];
    float* out = (float*)d_out;

    const int n      = in_sizes[0] / 2;   // 4,194,304 points
    const int nPairs = n / 32;            // 2 tiles of 16 points per wave-iter
    const int blocks = 4096;              // 16384 waves, 8 iters/wave, no tail
    const int nWaves = blocks * 4;

    artnet_kernel<<<blocks, 256, 0, stream>>>(x, Win, bin, Wh, Wout, out, nPairs, nWaves);
}